// Round 16
// baseline (452.723 us; speedup 1.0000x reference)
//
#include <hip/hip_runtime.h>

#define B_    16
#define LBL_  48
#define PRED_ 336
#define CIN_  7
#define L_    384
#define DM_   512
#define E_    2
#define DIN_  1024
#define N_    16
#define DCONV_ 4
#define DTR_  32
#define TF_   4
#define EPSF  1e-5f
// scan: 16 segments x 24 steps, chunks of 2
#define NSEG  16
#define SEGL  24
#define SC2   2
#define NCHK  12

typedef unsigned short u16;
typedef __attribute__((ext_vector_type(8))) short short8;
typedef __attribute__((ext_vector_type(4))) float f32x4;

__device__ __forceinline__ float bf2f(u16 u){
  union { float f; unsigned int i; } cv; cv.i = ((unsigned int)u) << 16; return cv.f;
}
__device__ __forceinline__ u16 f2bf(float f){
  union { float f; unsigned int i; } cv; cv.f = f;
  unsigned int x = cv.i;
  unsigned int lsb = (x >> 16) & 1u;
  x += 0x7fffu + lsb;
  return (u16)(x >> 16);
}
__device__ __forceinline__ float lo16(unsigned int v){
  union { float f; unsigned int i; } cv; cv.i = v << 16; return cv.f;
}
__device__ __forceinline__ float hi16(unsigned int v){
  union { float f; unsigned int i; } cv; cv.i = v & 0xffff0000u; return cv.f;
}

#define GLDS(g, l) __builtin_amdgcn_global_load_lds( \
    (const __attribute__((address_space(1))) void*)(g), \
    (__attribute__((address_space(3))) void*)(l), 16, 0, 0)

// ---- fp32 parameter block offsets inside d_ws (floats) ----
// INW/XPROJ/DTW/OUTW slots hold bf16 (u16) weights.
#define PO_XDEC   0
#define PO_XMARK  43008
#define PO_TOKW   67584
#define PO_TIMEF  78336
#define PO_NORMW  80384
#define PO_NORMB  81408
#define PO_INW    82432
#define PO_CONVW  2179584
#define PO_CONVB  2187776
#define PO_XPROJ  2189824
#define PO_DTW    2320896
#define PO_DTB    2386432
#define PO_ALOG   2388480
#define PO_DP     2421248
#define PO_OUTW   2423296
#define PO_FNW    3471872
#define PO_FNB    3472384
#define PO_HEADW  3472896
#define P_TOTAL   3476480
// ---- activation offsets (floats) ----
#define A_X    3476480
#define A_LNB  6622208
#define A_XZ   9767936
#define A_DT   22350848
#define A_DBC  28642304
#define A_MEAN 29078528
#define A_STD  29078640
#define A_DTR  29100032   /* bf16 [6144][32] dt_r side-buffer */

struct Ptrs { const void* p[18]; };

__device__ __forceinline__ float wredsum(float s){
  #pragma unroll
  for (int off = 32; off; off >>= 1) s += __shfl_xor(s, off, 64);
  return s;
}

__device__ __forceinline__ void qpowers(float q, float* p){
  float q2 = q*q;
  float q4 = q2*q2;
  float q8 = q4*q4;
  float q3 = q2*q;
  p[0]=q;      p[1]=q2;     p[2]=q3;     p[3]=q4;
  p[4]=q4*q;   p[5]=q4*q2;  p[6]=q4*q3;  p[7]=q8;
  p[8]=q8*q;   p[9]=q8*q2;  p[10]=q8*q3; p[11]=q8*q4;
  p[12]=q8*p[4]; p[13]=q8*p[5]; p[14]=q8*p[6]; p[15]=q8*q8;
}

// ---------------- dtype-agnostic input conversion ----------------
__global__ __launch_bounds__(256) void convert_kernel(Ptrs ps, float* __restrict__ dst){
  const int offs[18] = {PO_XDEC, PO_XMARK, PO_TOKW, PO_TIMEF, PO_NORMW, PO_NORMB,
                        PO_INW, PO_CONVW, PO_CONVB, PO_XPROJ, PO_DTW, PO_DTB,
                        PO_ALOG, PO_DP, PO_OUTW, PO_FNW, PO_FNB, PO_HEADW};
  int idx = blockIdx.x * 256 + threadIdx.x;
  if (idx >= P_TOTAL) return;
  int seg = 0;
  #pragma unroll
  for (int s = 1; s < 18; s++) if (idx >= offs[s]) seg = s;
  int off = idx - offs[seg];
  int isbf = (((const u16*)ps.p[4])[0] == 0x3F80u);
  if (seg == 6 || seg == 9 || seg == 10 || seg == 14){
    u16 hv = isbf ? ((const u16*)ps.p[seg])[off]
                  : f2bf(((const float*)ps.p[seg])[off]);
    ((u16*)(dst + offs[seg]))[off] = hv;
  } else {
    float v = isbf ? bf2f(((const u16*)ps.p[seg])[off])
                   : ((const float*)ps.p[seg])[off];
    dst[idx] = v;
  }
}

// ------- fused head-stats + token embed + LayerNorm(e=0): wave per token -------
// Recomputes batch head-stats per wave from RAW x_dec (exact prep arithmetic),
// normalizes its conv taps inline, writes fp32 x, bf16 lnxb, and meanv/stdv.
__global__ __launch_bounds__(256) void embed_ln_kernel(const void* __restrict__ xdec,
      const u16* __restrict__ dtype_probe,
      const float* __restrict__ token_w, const float* __restrict__ x_mark,
      const float* __restrict__ timef_w, const float* __restrict__ nw,
      const float* __restrict__ nb, float* __restrict__ x, u16* __restrict__ out,
      float* __restrict__ meanv, float* __restrict__ stdv){
  int isbf = (dtype_probe[0] == 0x3F80u);
  int tok = blockIdx.x*4 + (threadIdx.x >> 6);
  int lane = threadIdx.x & 63;
  int t = tok % L_;
  int b = tok / L_;
  float xv[CIN_];
  #pragma unroll
  for (int c = 0; c < CIN_; c++){
    float v = 0.f;
    if (lane < LBL_)
      v = isbf ? bf2f(((const u16*)xdec)[(b*L_+lane)*CIN_+c])
               : ((const float*)xdec)[(b*L_+lane)*CIN_+c];
    xv[c] = v;
  }
  float m[CIN_], inv[CIN_], sd[CIN_];
  #pragma unroll
  for (int c = 0; c < CIN_; c++){
    float mm = wredsum(xv[c]) * (1.f/LBL_);
    float dv = (lane < LBL_) ? (xv[c] - mm) : 0.f;
    float vv = wredsum(dv*dv) * (1.f/LBL_);
    float s = sqrtf(vv + EPSF);
    m[c] = mm; sd[c] = s; inv[c] = 1.f/s;
  }
  if (lane == 0){
    #pragma unroll
    for (int c = 0; c < CIN_; c++){ meanv[b*CIN_+c] = m[c]; stdv[b*CIN_+c] = sd[c]; }
  }
  int tm1 = (t == 0) ? L_-1 : t-1;
  int tp1 = (t == L_-1) ? 0 : t+1;
  float a0[CIN_], a1[CIN_], a2[CIN_], mkv[TF_];
  #pragma unroll
  for (int c = 0; c < CIN_; c++){
    float v0 = isbf ? bf2f(((const u16*)xdec)[(b*L_+tm1)*CIN_+c]) : ((const float*)xdec)[(b*L_+tm1)*CIN_+c];
    float v1 = isbf ? bf2f(((const u16*)xdec)[(b*L_+t  )*CIN_+c]) : ((const float*)xdec)[(b*L_+t  )*CIN_+c];
    float v2 = isbf ? bf2f(((const u16*)xdec)[(b*L_+tp1)*CIN_+c]) : ((const float*)xdec)[(b*L_+tp1)*CIN_+c];
    a0[c] = (tm1 < LBL_) ? (v0 - m[c]) * inv[c] : v0;
    a1[c] = (t   < LBL_) ? (v1 - m[c]) * inv[c] : v1;
    a2[c] = (tp1 < LBL_) ? (v2 - m[c]) * inv[c] : v2;
  }
  #pragma unroll
  for (int f = 0; f < TF_; f++) mkv[f] = x_mark[(b*L_+t)*TF_+f];
  float v[8];
  #pragma unroll
  for (int j = 0; j < 8; j++){
    int d = lane*8 + j;
    float acc = 0.f;
    #pragma unroll
    for (int ci = 0; ci < CIN_; ci++){
      const float* w = token_w + (d*CIN_+ci)*3;
      acc += a0[ci]*w[0] + a1[ci]*w[1] + a2[ci]*w[2];
    }
    #pragma unroll
    for (int f = 0; f < TF_; f++)
      acc += mkv[f] * timef_w[d*TF_+f];
    v[j] = acc;
  }
  float* xr = x + (size_t)tok*DM_ + lane*8;
  *(float4*)xr       = (float4){v[0],v[1],v[2],v[3]};
  *(float4*)(xr + 4) = (float4){v[4],v[5],v[6],v[7]};
  float s = (v[0]+v[1])+(v[2]+v[3])+((v[4]+v[5])+(v[6]+v[7]));
  float mean = wredsum(s) * (1.f/DM_);
  float s2 = 0.f;
  #pragma unroll
  for (int j = 0; j < 8; j++){ v[j] -= mean; s2 += v[j]*v[j]; }
  float rstd = rsqrtf(wredsum(s2) * (1.f/DM_) + EPSF);
  const float* wr = nw + lane*8;
  const float* br = nb + lane*8;
  uint4 o; unsigned int* op = (unsigned int*)&o;
  #pragma unroll
  for (int k = 0; k < 4; k++){
    u16 e0 = f2bf(v[2*k]   * rstd * wr[2*k]   + br[2*k]);
    u16 e1 = f2bf(v[2*k+1] * rstd * wr[2*k+1] + br[2*k+1]);
    op[k] = (unsigned int)e0 | ((unsigned int)e1 << 16);
  }
  *(uint4*)(out + (size_t)tok*DM_ + lane*8) = o;
}

// ---------------- layer norm over DM=512 -> bf16, wave per token ----------------
__global__ __launch_bounds__(256) void ln_kernel(const float* __restrict__ x,
     const float* __restrict__ w, const float* __restrict__ bias, u16* __restrict__ out){
  int tok = blockIdx.x*4 + (threadIdx.x >> 6);
  int lane = threadIdx.x & 63;
  const float* xr = x + (size_t)tok*DM_ + lane*8;
  float4 a = *(const float4*)xr;
  float4 bq = *(const float4*)(xr + 4);
  float v[8] = {a.x,a.y,a.z,a.w,bq.x,bq.y,bq.z,bq.w};
  float s = (v[0]+v[1])+(v[2]+v[3])+((v[4]+v[5])+(v[6]+v[7]));
  float mean = wredsum(s) * (1.f/DM_);
  float s2 = 0.f;
  #pragma unroll
  for (int j = 0; j < 8; j++){ v[j] -= mean; s2 += v[j]*v[j]; }
  float rstd = rsqrtf(wredsum(s2) * (1.f/DM_) + EPSF);
  const float* wr = w + lane*8;
  const float* br = bias + lane*8;
  uint4 o; unsigned int* op = (unsigned int*)&o;
  #pragma unroll
  for (int k = 0; k < 4; k++){
    u16 e0 = f2bf(v[2*k]   * rstd * wr[2*k]   + br[2*k]);
    u16 e1 = f2bf(v[2*k+1] * rstd * wr[2*k+1] + br[2*k+1]);
    op[k] = (unsigned int)e0 | ((unsigned int)e1 << 16);
  }
  *(uint4*)(out + (size_t)tok*DM_ + lane*8) = o;
}

// ---------------- MFMA GEMM, BK=64: C[M,N] (+)= A[M,K](bf16) * W[N,K](bf16)^T ----------------
template<int TN, int ACCUM, int BF16OUT, int DTR>
__global__ __launch_bounds__(256) void gemm_mfma(const u16* __restrict__ A, const u16* __restrict__ Wt,
    void* __restrict__ C, int M, int N, int K, u16* __restrict__ dtrb){
  constexpr int WN = TN / 2;
  constexpr int NI = WN / 16;
  __shared__ u16 As[128 * 64];
  __shared__ u16 Ws[TN * 64];
  int tid = threadIdx.x;
  int wv = tid >> 6, lane = tid & 63;
  int wm = (wv & 1) * 64, wn = (wv >> 1) * WN;
  int m0 = blockIdx.y * 128, n0 = blockIdx.x * TN;
  int la = lane & 15, lk = lane >> 4;
  f32x4 acc[4][NI];
  #pragma unroll
  for (int i = 0; i < 4; i++)
    #pragma unroll
    for (int j = 0; j < NI; j++) acc[i][j] = (f32x4){0.f, 0.f, 0.f, 0.f};
  int srow = lane >> 3, scol = (lane & 7) * 8;   // 8 rows x 64 cols per GLDS
  const u16* Ag = A + (size_t)(m0 + wv*32 + srow) * K + scol;
  u16* Al = As + wv*2048 + lane*8;
  const u16* Wg;
  u16* Wl;
  if constexpr (TN == 128){
    Wg = Wt + (size_t)(n0 + wv*32 + srow) * K + scol;
    Wl = Ws + wv*2048 + lane*8;
  } else {
    Wg = Wt + (size_t)(n0 + wv*16 + srow) * K + scol;
    Wl = Ws + wv*1024 + lane*8;
  }
  for (int k0 = 0; k0 < K; k0 += 64){
    #pragma unroll
    for (int i = 0; i < 4; i++) GLDS(Ag + k0 + (size_t)i*8*K, Al + i*512);
    if constexpr (TN == 128){
      #pragma unroll
      for (int i = 0; i < 4; i++) GLDS(Wg + k0 + (size_t)i*8*K, Wl + i*512);
    } else {
      #pragma unroll
      for (int i = 0; i < 2; i++) GLDS(Wg + k0 + (size_t)i*8*K, Wl + i*512);
    }
    __syncthreads();
    #pragma unroll
    for (int ks = 0; ks < 2; ks++){
      short8 af[4], bfr[NI];
      #pragma unroll
      for (int mi = 0; mi < 4; mi++) af[mi] = *(const short8*)&As[(wm + mi*16 + la)*64 + ks*32 + lk*8];
      #pragma unroll
      for (int ni = 0; ni < NI; ni++) bfr[ni] = *(const short8*)&Ws[(wn + ni*16 + la)*64 + ks*32 + lk*8];
      #pragma unroll
      for (int mi = 0; mi < 4; mi++)
        #pragma unroll
        for (int ni = 0; ni < NI; ni++)
          acc[mi][ni] = __builtin_amdgcn_mfma_f32_16x16x32_bf16(af[mi], bfr[ni], acc[mi][ni], 0, 0, 0);
    }
    __syncthreads();
  }
  #pragma unroll
  for (int mi = 0; mi < 4; mi++)
    #pragma unroll
    for (int ni = 0; ni < NI; ni++){
      int row = m0 + wm + mi*16 + lk*4;
      int col = n0 + wn + ni*16 + la;
      #pragma unroll
      for (int r = 0; r < 4; r++){
        if constexpr (BF16OUT){
          u16* p = (u16*)C + (size_t)row * N + col;
          p[(size_t)r * N] = f2bf(acc[mi][ni][r]);
        } else {
          float* p = (float*)C + (size_t)row * N + col;
          if (ACCUM) p[(size_t)r * N] += acc[mi][ni][r];
          else       p[(size_t)r * N]  = acc[mi][ni][r];
        }
      }
    }
  if constexpr (DTR){
    if (wn == 0){
      #pragma unroll
      for (int mi = 0; mi < 4; mi++)
        #pragma unroll
        for (int ni = 0; ni < NI; ni++){
          int row = m0 + wm + mi*16 + lk*4;
          int col = ni*16 + la;
          #pragma unroll
          for (int r = 0; r < 4; r++)
            dtrb[(size_t)(row + r)*32 + col] = f2bf(acc[mi][ni][r]);
        }
    }
  }
}

// ---------------- dtproj as MFMA: dt = softplus(dt_r @ dtw^T + b), K=32 ----------------
__global__ __launch_bounds__(256) void dtproj_mfma(const u16* __restrict__ dtrb,
    const u16* __restrict__ dtwb, const float* __restrict__ dtb, u16* __restrict__ dt){
  __shared__ u16 As[128 * 32];
  __shared__ u16 Ws[64 * 32];
  int tid = threadIdx.x;
  int wv = tid >> 6, lane = tid & 63;
  int wm = (wv & 1) * 64, wn = (wv >> 1) * 32;
  int m0 = blockIdx.y * 128, n0 = blockIdx.x * 64;
  int la = lane & 15, lk = lane >> 4;
  int srow = lane >> 2, scol = (lane & 3) * 8;
  GLDS(dtrb + (size_t)(m0 + wv*32 + srow)*32 + scol,      As + wv*1024 + lane*8);
  GLDS(dtrb + (size_t)(m0 + wv*32 + 16 + srow)*32 + scol, As + wv*1024 + 512 + lane*8);
  GLDS(dtwb + (size_t)(n0 + wv*16 + srow)*32 + scol,      Ws + wv*512 + lane*8);
  __syncthreads();
  short8 af[4], bfr[2];
  #pragma unroll
  for (int mi = 0; mi < 4; mi++) af[mi] = *(const short8*)&As[(wm + mi*16 + la)*32 + lk*8];
  #pragma unroll
  for (int ni = 0; ni < 2; ni++) bfr[ni] = *(const short8*)&Ws[(wn + ni*16 + la)*32 + lk*8];
  #pragma unroll
  for (int mi = 0; mi < 4; mi++)
    #pragma unroll
    for (int ni = 0; ni < 2; ni++){
      f32x4 acc = (f32x4){0.f,0.f,0.f,0.f};
      acc = __builtin_amdgcn_mfma_f32_16x16x32_bf16(af[mi], bfr[ni], acc, 0, 0, 0);
      int row = m0 + wm + mi*16 + lk*4;
      int d   = n0 + wn + ni*16 + la;
      float bias = dtb[d];
      #pragma unroll
      for (int r = 0; r < 4; r++){
        float raw = acc[r] + bias;
        float sp = (raw > 20.f) ? raw : log1pf(__expf(raw));
        dt[(size_t)(row + r)*DIN_ + d] = f2bf(sp);
      }
    }
}

// ---------------- depthwise causal conv (k=4) + SiLU: 8 channels/thread ----------------
__global__ __launch_bounds__(256) void conv_silu_kernel(const u16* __restrict__ xz,
   const float* __restrict__ cw, const float* __restrict__ cb, u16* __restrict__ xcb){
  int e = blockIdx.x * 256 + threadIdx.x;
  int c8 = (e & (DIN_/8 - 1)) * 8;
  int bt = e >> 7;
  int t  = bt % L_;
  const u16* base = xz + (size_t)bt * (2*DIN_) + c8;
  uint4 tap[4];
  tap[3] = *(const uint4*)base;
  if (t >= 1) tap[2] = *(const uint4*)(base - 1*2*DIN_);
  if (t >= 2) tap[1] = *(const uint4*)(base - 2*2*DIN_);
  if (t >= 3) tap[0] = *(const uint4*)(base - 3*2*DIN_);
  float v[8];
  #pragma unroll
  for (int k = 0; k < 8; k++){
    float4 w = *(const float4*)(cw + (c8 + k)*4);
    float s = cb[c8 + k];
    #pragma unroll
    for (int j = 0; j < 4; j++){
      if (j >= 3 - t){
        const unsigned int* tp = (const unsigned int*)&tap[j];
        float xv = (k & 1) ? hi16(tp[k >> 1]) : lo16(tp[k >> 1]);
        s += xv * ((const float*)&w)[j];
      }
    }
    v[k] = s / (1.f + __expf(-s));
  }
  uint4 o;
  unsigned int* op = (unsigned int*)&o;
  #pragma unroll
  for (int k = 0; k < 4; k++)
    op[k] = (unsigned int)f2bf(v[2*k]) | ((unsigned int)f2bf(v[2*k+1]) << 16);
  *(uint4*)(xcb + (size_t)bt * DIN_ + c8) = o;
}

// ---------------- selective scan: 16 segments x 24 steps, 2-pass, 16 states/thread ----------------
#define WSTR2 896
__global__ __launch_bounds__(1024, 1) void scan_kernel(
    u16* __restrict__ ub_yb,
    const float* __restrict__ dbc, const u16* __restrict__ xz,
    const u16* __restrict__ dtp,
    const float* __restrict__ A_log, const float* __restrict__ Dp){
  __shared__ float smem[16384];

  int tid = threadIdx.x;
  int lane = tid & 63;
  int seg  = tid >> 6;
  int b = blockIdx.x >> 4;
  int g = blockIdx.x & 15;
  int d = g*64 + lane;
  size_t base = (size_t)b * L_;

  float* wbase = smem + seg * WSTR2;
  float* sbc = wbase;
  float* su  = wbase + 128;
  float* sz  = wbase + 384;
  float* sdt = wbase + 640;

  int st = lane >> 5;
  int j  = lane & 31;

  float A[16];
  #pragma unroll
  for (int n = 0; n < 16; n += 4){
    float4 av = *(const float4*)(A_log + (size_t)d*N_ + n);
    A[n] = -__expf(av.x); A[n+1] = -__expf(av.y); A[n+2] = -__expf(av.z); A[n+3] = -__expf(av.w);
  }
  float Dv = Dp[d];
  bool fastA = true;
  #pragma unroll
  for (int n = 0; n < 16; n++) fastA = fastA && (fabsf(A[n] + (float)(n+1)) < 1e-3f*(n+1));

  float h[16];
  #pragma unroll
  for (int n = 0; n < 16; n++) h[n] = 0.f;

  auto ldc = [&](int c, float& kbc, unsigned int& ku, unsigned int& kz,
                 unsigned int& kt, bool wz){
    size_t tokr = base + seg*SEGL + c*SC2 + st;
    kbc = dbc[tokr*64 + 32 + j];
    ku  = ((const unsigned int*)(ub_yb + tokr*DIN_ + g*64))[j];
    kt  = ((const unsigned int*)(dtp + tokr*DIN_ + g*64))[j];
    if (wz) kz = ((const unsigned int*)(xz + tokr*(2*DIN_) + DIN_ + g*64))[j];
  };
  auto stc = [&](int buf, float kbc, unsigned int ku, unsigned int kz,
                 unsigned int kt, bool wz){
    sbc[buf*64 + st*32 + j] = kbc;
    su [buf*128 + st*64 + 2*j]     = lo16(ku);
    su [buf*128 + st*64 + 2*j + 1] = hi16(ku);
    sdt[buf*128 + st*64 + 2*j]     = lo16(kt);
    sdt[buf*128 + st*64 + 2*j + 1] = hi16(kt);
    if (wz){
      sz[buf*128 + st*64 + 2*j]     = lo16(kz);
      sz[buf*128 + st*64 + 2*j + 1] = hi16(kz);
    }
  };

  // PASS 1
  float S = 0.f;
  {
    float kbc; unsigned int ku, kz, kt;
    ldc(0, kbc, ku, kz, kt, false);
    stc(0, kbc, ku, kz, kt, false);
    for (int c = 0; c < NCHK; c++){
      int cur = c & 1;
      bool have = (c + 1 < NCHK);
      float nbc; unsigned int nu, nz, nt;
      if (have) ldc(c+1, nbc, nu, nz, nt, false);
      for (int s = 0; s < SC2; s++){
        float dtv = sdt[cur*128 + s*64 + lane];
        float u   = su [cur*128 + s*64 + lane];
        const float* bcrow = sbc + cur*64 + s*32;
        float Bf[16];
        #pragma unroll
        for (int i = 0; i < 16; i += 4){
          float4 bv = *(const float4*)(bcrow + i);
          Bf[i] = bv.x; Bf[i+1] = bv.y; Bf[i+2] = bv.z; Bf[i+3] = bv.w;
        }
        float du = dtv * u;
        S += dtv;
        if (fastA){
          float q = __expf(-dtv);
          float p[16];
          qpowers(q, p);
          #pragma unroll
          for (int n = 0; n < 16; n++) h[n] = p[n] * h[n] + du * Bf[n];
        } else {
          #pragma unroll
          for (int n = 0; n < 16; n++){
            float dA = __expf(dtv * A[n]);
            h[n] = dA * h[n] + du * Bf[n];
          }
        }
      }
      if (have) stc(1 - cur, nbc, nu, nz, nt, false);
    }
  }

  // combine, two n-halves
  #pragma unroll
  for (int half = 0; half < 2; half++){
    __syncthreads();
    #pragma unroll
    for (int n = 0; n < 8; n++){
      int nn = half*8 + n;
      smem[(n*NSEG + seg)*64 + lane]        = h[nn];
      smem[8192 + (n*NSEG + seg)*64 + lane] = __expf(A[nn] * S);
    }
    __syncthreads();
    float hs[8];
    #pragma unroll
    for (int n = 0; n < 8; n++) hs[n] = 0.f;
    for (int jj = 0; jj < seg; jj++){
      #pragma unroll
      for (int n = 0; n < 8; n++){
        float qh = smem[(n*NSEG + jj)*64 + lane];
        float qP = smem[8192 + (n*NSEG + jj)*64 + lane];
        hs[n] = qh + qP * hs[n];
      }
    }
    #pragma unroll
    for (int n = 0; n < 8; n++) h[half*8 + n] = hs[n];
  }
  __syncthreads();

  // PASS 2
  {
    float kbc; unsigned int ku, kz, kt;
    ldc(0, kbc, ku, kz, kt, true);
    stc(0, kbc, ku, kz, kt, true);
    for (int c = 0; c < NCHK; c++){
      int cur = c & 1;
      bool have = (c + 1 < NCHK);
      float nbc; unsigned int nu, nz, nt;
      if (have) ldc(c+1, nbc, nu, nz, nt, true);
      for (int s = 0; s < SC2; s++){
        float dtv = sdt[cur*128 + s*64 + lane];
        float u   = su [cur*128 + s*64 + lane];
        float z   = sz [cur*128 + s*64 + lane];
        const float* bcrow = sbc + cur*64 + s*32;
        float Bf[16], Cf[16];
        #pragma unroll
        for (int i = 0; i < 16; i += 4){
          float4 bv = *(const float4*)(bcrow + i);
          float4 cv = *(const float4*)(bcrow + 16 + i);
          Bf[i] = bv.x; Bf[i+1] = bv.y; Bf[i+2] = bv.z; Bf[i+3] = bv.w;
          Cf[i] = cv.x; Cf[i+1] = cv.y; Cf[i+2] = cv.z; Cf[i+3] = cv.w;
        }
        float du = dtv * u;
        float acc = 0.f;
        if (fastA){
          float q = __expf(-dtv);
          float p[16];
          qpowers(q, p);
          #pragma unroll
          for (int n = 0; n < 16; n++){
            h[n] = p[n] * h[n] + du * Bf[n];
            acc += h[n] * Cf[n];
          }
        } else {
          #pragma unroll
          for (int n = 0; n < 16; n++){
            float dA = __expf(dtv * A[n]);
            h[n] = dA * h[n] + du * Bf[n];
            acc += h[n] * Cf[n];
          }
        }
        float y = acc + u * Dv;
        size_t tok = base + seg*SEGL + c*SC2 + s;
        ub_yb[tok*DIN_ + d] = f2bf(y * (z / (1.f + __expf(-z))));
      }
      if (have) stc(1 - cur, nbc, nu, nz, nt, true);
    }
  }
}

// ---------------- final LN + 512->7 head + de-normalize, wave per token ----------------
__global__ __launch_bounds__(256) void head_kernel(const float* __restrict__ x,
    const float* __restrict__ fw, const float* __restrict__ fb, const float* __restrict__ ow,
    const float* __restrict__ meanv, const float* __restrict__ stdv, void* __restrict__ out,
    const u16* __restrict__ dtype_probe){
  int wav = blockIdx.x*4 + (threadIdx.x >> 6);
  int lane = threadIdx.x & 63;
  if (wav >= B_*PRED_) return;
  int b = wav / PRED_;
  int tt = wav % PRED_;
  int tok = b*L_ + LBL_ + tt;
  const float* xr = x + (size_t)tok*DM_ + lane*8;
  float4 a = *(const float4*)xr;
  float4 bq = *(const float4*)(xr + 4);
  float v[8] = {a.x,a.y,a.z,a.w,bq.x,bq.y,bq.z,bq.w};
  float s = (v[0]+v[1])+(v[2]+v[3])+((v[4]+v[5])+(v[6]+v[7]));
  float mean = wredsum(s) * (1.f/DM_);
  float s2 = 0.f;
  #pragma unroll
  for (int j = 0; j < 8; j++){ v[j] -= mean; s2 += v[j]*v[j]; }
  float rstd = rsqrtf(wredsum(s2) * (1.f/DM_) + EPSF);
  const float* fwr = fw + lane*8;
  const float* fbr = fb + lane*8;
  #pragma unroll
  for (int j = 0; j < 8; j++) v[j] = v[j] * rstd * fwr[j] + fbr[j];
  int isbf = (dtype_probe[0] == 0x3F80u);
  for (int o = 0; o < CIN_; o++){
    const float* owr = ow + (size_t)o*DM_ + lane*8;
    float part = 0.f;
    #pragma unroll
    for (int j = 0; j < 8; j++) part += v[j] * owr[j];
    part = wredsum(part);
    if (lane == 0){
      float res = part * stdv[b*CIN_ + o] + meanv[b*CIN_ + o];
      size_t oidx = (size_t)(b*PRED_ + tt)*CIN_ + o;
      if (isbf) ((u16*)out)[oidx] = f2bf(res);
      else      ((float*)out)[oidx] = res;
    }
  }
}

extern "C" void kernel_launch(void* const* d_in, const int* in_sizes, int n_in,
                              void* d_out, int out_size, void* d_ws, size_t ws_size,
                              hipStream_t stream){
  float* P = (float*)d_ws;

  Ptrs ps;
  for (int i = 0; i < 18; i++) ps.p[i] = d_in[2 + i];

  float* x    = P + A_X;
  u16*   lnxb = (u16*)(P + A_LNB);
  u16*   xcb  = (u16*)(P + A_LNB);
  u16*   xz   = (u16*)(P + A_XZ);
  u16*   dt   = (u16*)(P + A_DT);
  u16*   dtrb = (u16*)(P + A_DTR);
  float* dbc  = P + A_DBC;
  float* meanv= P + A_MEAN;
  float* stdv = P + A_STD;
  const u16* bwi = (const u16*)(P + PO_INW);
  const u16* bwx = (const u16*)(P + PO_XPROJ);
  const u16* bwd = (const u16*)(P + PO_DTW);
  const u16* bwo = (const u16*)(P + PO_OUTW);
  const u16* probe = (const u16*)d_in[6];

  convert_kernel<<<(P_TOTAL+255)/256, 256, 0, stream>>>(ps, P);
  // x_dec raw pointer is d_in[2]  (round-15 bug: d_in[4] was token_w)
  embed_ln_kernel<<<(B_*L_)/4, 256, 0, stream>>>(
      d_in[2], probe, P + PO_TOKW, P + PO_XMARK, P + PO_TIMEF,
      P + PO_NORMW, P + PO_NORMB, x, lnxb, meanv, stdv);

  for (int e = 0; e < E_; e++){
    if (e > 0)
      ln_kernel<<<(B_*L_)/4, 256, 0, stream>>>(x, P + PO_NORMW + e*DM_, P + PO_NORMB + e*DM_, lnxb);
    gemm_mfma<128,0,1,0><<<dim3((2*DIN_)/128, (B_*L_)/128), 256, 0, stream>>>(
        lnxb, bwi + (size_t)e*2*DIN_*DM_, xz, B_*L_, 2*DIN_, DM_, nullptr);
    conv_silu_kernel<<<(B_*L_*DIN_)/(256*8), 256, 0, stream>>>(
        xz, P + PO_CONVW + e*DIN_*DCONV_, P + PO_CONVB + e*DIN_, xcb);
    gemm_mfma<64,0,0,1><<<dim3(1, (B_*L_)/128), 256, 0, stream>>>(
        xcb, bwx + (size_t)e*64*DIN_, dbc, B_*L_, 64, DIN_, dtrb);
    dtproj_mfma<<<dim3(DIN_/64, (B_*L_)/128), 256, 0, stream>>>(
        dtrb, bwd + (size_t)e*DIN_*DTR_, P + PO_DTB + e*DIN_, dt);
    scan_kernel<<<256, 1024, 0, stream>>>(
        xcb, dbc, xz, dt, P + PO_ALOG + e*DIN_*N_, P + PO_DP + e*DIN_);
    gemm_mfma<64,1,0,0><<<dim3(DM_/64, (B_*L_)/128), 256, 0, stream>>>(
        xcb, bwo + (size_t)e*DM_*DIN_, x, B_*L_, DM_, DIN_, nullptr);
  }

  head_kernel<<<(B_*PRED_+3)/4, 256, 0, stream>>>(
      x, P + PO_FNW, P + PO_FNB, P + PO_HEADW, meanv, stdv, d_out, probe);
}